// Round 1
// baseline (1260.120 us; speedup 1.0000x reference)
//
#include <hip/hip_runtime.h>

typedef __bf16 bf16x8 __attribute__((ext_vector_type(8)));
typedef float  f32x4  __attribute__((ext_vector_type(4)));

// ---- constants for this problem ----
#define MDIM 16384   // B*T = 8*2048
#define NDIM 4096    // OUT
#define KDIM 4096    // IN

static __device__ __forceinline__ unsigned short f2bf(float f) {
  // round-to-nearest-even f32 -> bf16 bits (inputs are finite)
  unsigned int u = __float_as_uint(f);
  unsigned int r = (u + 0x7FFFu + ((u >> 16) & 1u)) >> 16;
  return (unsigned short)r;
}

static __device__ __forceinline__ void g2l16(const unsigned short* g, unsigned short* l) {
  __builtin_amdgcn_global_load_lds(
      (const __attribute__((address_space(1))) void*)g,
      (__attribute__((address_space(3))) void*)l, 16, 0, 0);
}

// ---------------------------------------------------------------------------
// Kernel 1: W_eff[o,i] = W[o,i] + sum_j W[ai*64+oi, bj*64+j]*bone[bj,j,k] + bone[bj,oi,k]
// (o = ai*64+oi, i = bj*64+k), output bf16. One block per (ai,bj) 64x64 tile.
// ---------------------------------------------------------------------------
__global__ __launch_bounds__(256) void wtrans_kernel(
    const float* __restrict__ W, const float* __restrict__ bone,
    unsigned short* __restrict__ Weff) {
  __shared__ float Wb[64][64];
  __shared__ float Bn[64][65];
  const int ai = blockIdx.y, bj = blockIdx.x;
  const int t = threadIdx.x;
#pragma unroll
  for (int rr = 0; rr < 16; ++rr) {
    int idx = rr * 256 + t;
    int r = idx >> 6, c = idx & 63;
    Wb[r][c] = W[(size_t)(ai * 64 + r) * KDIM + bj * 64 + c];
    Bn[r][c] = bone[(size_t)(bj * 64 + r) * 64 + c];
  }
  __syncthreads();
#pragma unroll 1
  for (int rr = 0; rr < 16; ++rr) {
    int idx = rr * 256 + t;
    int oi = idx >> 6, k = idx & 63;   // per wave: oi uniform, k = lane (conflict-free)
    float s = Wb[oi][k] + Bn[oi][k];
#pragma unroll
    for (int j = 0; j < 64; ++j) s += Wb[oi][j] * Bn[j][k];
    Weff[(size_t)(ai * 64 + oi) * KDIM + bj * 64 + k] = f2bf(s);
  }
}

// ---------------------------------------------------------------------------
// Kernel 2: x f32 -> bf16, vectorized (float4 in, ushort4 out)
// ---------------------------------------------------------------------------
__global__ __launch_bounds__(256) void xconv_kernel(
    const float4* __restrict__ X, ushort4* __restrict__ Xb, int n4) {
  int i = blockIdx.x * blockDim.x + threadIdx.x;
  int stride = gridDim.x * blockDim.x;
  for (; i < n4; i += stride) {
    float4 v = X[i];
    ushort4 o;
    o.x = f2bf(v.x); o.y = f2bf(v.y); o.z = f2bf(v.z); o.w = f2bf(v.w);
    Xb[i] = o;
  }
}

// ---------------------------------------------------------------------------
// Kernel 3: C[m,n] = sum_k A[m,k]*B[n,k]   (A: MxK bf16, B: NxK bf16, C f32)
// m97 structure: 128x128 tile, BK=64, 4 waves (2x2), global_load_lds width=16,
// linear LDS, 2 barriers per K-step. ~870-910 TF class on gfx950.
// ---------------------------------------------------------------------------
#define BM 128
#define BN 128
#define BK 64

__global__ __launch_bounds__(256) void gemm_bt_kernel(
    const unsigned short* __restrict__ A,   // M x K bf16 bits
    const unsigned short* __restrict__ B,   // N x K bf16 bits
    float* __restrict__ C) {
  __shared__ __attribute__((aligned(16))) unsigned short As[BM][BK];
  __shared__ __attribute__((aligned(16))) unsigned short Bs[BN][BK];

  const int t = threadIdx.x;
  const int lane = t & 63;
  const int w = t >> 6;             // 0..3
  const int wm = w >> 1, wn = w & 1;

  const int m0 = blockIdx.y * BM;
  const int n0 = blockIdx.x * BN;

  // staging: chunk idx = it*256 + t covers 16B; row = idx>>3, col=(idx&7)*8 elems.
  // Per wave: lds dest = wave-uniform base + lane*16 (linear) -- matches HW rule.
  const int sr = t >> 3;            // 0..31, +32 per issue
  const int sc = (t & 7) * 8;

  const unsigned short* Ag = A + (size_t)(m0 + sr) * KDIM + sc;
  const unsigned short* Bg = B + (size_t)(n0 + sr) * KDIM + sc;
  unsigned short* Al = &As[sr][sc];
  unsigned short* Bl = &Bs[sr][sc];

  f32x4 acc[4][4] = {};

  const int fr = lane & 15;         // fragment row (M for A, N for B)
  const int fk = (lane >> 4) * 8;   // k offset within 32

  for (int k0 = 0; k0 < KDIM; k0 += BK) {
#pragma unroll
    for (int it = 0; it < 4; ++it)
      g2l16(Ag + (size_t)(it * 32) * KDIM + k0, Al + it * 32 * BK);
#pragma unroll
    for (int it = 0; it < 4; ++it)
      g2l16(Bg + (size_t)(it * 32) * KDIM + k0, Bl + it * 32 * BK);
    __syncthreads();   // drains vmcnt (global_load_lds) + lgkm

#pragma unroll
    for (int kk = 0; kk < 2; ++kk) {
      bf16x8 a[4], b[4];
#pragma unroll
      for (int mf = 0; mf < 4; ++mf)
        a[mf] = *(const bf16x8*)&As[wm * 64 + mf * 16 + fr][kk * 32 + fk];
#pragma unroll
      for (int nf = 0; nf < 4; ++nf)
        b[nf] = *(const bf16x8*)&Bs[wn * 64 + nf * 16 + fr][kk * 32 + fk];
#pragma unroll
      for (int mf = 0; mf < 4; ++mf)
#pragma unroll
        for (int nf = 0; nf < 4; ++nf)
          acc[mf][nf] = __builtin_amdgcn_mfma_f32_16x16x32_bf16(
              a[mf], b[nf], acc[mf][nf], 0, 0, 0);
    }
    __syncthreads();
  }

  // epilogue: C/D layout col=lane&15, row=(lane>>4)*4+reg (m89-verified)
  const int cr = (lane >> 4) * 4;
  const int cc = lane & 15;
#pragma unroll
  for (int mf = 0; mf < 4; ++mf) {
#pragma unroll
    for (int nf = 0; nf < 4; ++nf) {
      float* cp = C + (size_t)(m0 + wm * 64 + mf * 16 + cr) * NDIM
                    + (n0 + wn * 64 + nf * 16 + cc);
#pragma unroll
      for (int r = 0; r < 4; ++r) cp[(size_t)r * NDIM] = acc[mf][nf][r];
    }
  }
}

// ---------------------------------------------------------------------------
extern "C" void kernel_launch(void* const* d_in, const int* in_sizes, int n_in,
                              void* d_out, int out_size, void* d_ws, size_t ws_size,
                              hipStream_t stream) {
  const float* x      = (const float*)d_in[0];   // (8,2048,4096) f32
  const float* weight = (const float*)d_in[1];   // (4096,4096) f32
  const float* bone   = (const float*)d_in[2];   // (64,64,64) f32
  float* out = (float*)d_out;                    // (16384,4096) f32

  // workspace layout: [Weff bf16: 4096*4096] [Xb bf16: 16384*4096]  = 167.8 MB
  unsigned short* Weff = (unsigned short*)d_ws;
  unsigned short* Xb   = (unsigned short*)d_ws + (size_t)NDIM * KDIM;

  dim3 g1(64, 64);
  wtrans_kernel<<<g1, 256, 0, stream>>>(weight, bone, Weff);

  int n4 = (MDIM * KDIM) / 4;
  xconv_kernel<<<2048, 256, 0, stream>>>((const float4*)x, (ushort4*)Xb, n4);

  dim3 g3(NDIM / BN, MDIM / BM);
  gemm_bt_kernel<<<g3, 256, 0, stream>>>(Xb, Weff, out);
}